// Round 9
// baseline (304.206 us; speedup 1.0000x reference)
//
#include <hip/hip_runtime.h>

typedef __attribute__((ext_vector_type(4))) float f32x4;
typedef __attribute__((ext_vector_type(8))) _Float16 f16x8;
typedef __attribute__((ext_vector_type(4))) _Float16 f16x4;

static __device__ __forceinline__ f32x4 mfma16f(f16x8 a, f16x8 b, f32x4 c) {
    return __builtin_amdgcn_mfma_f32_16x16x32_f16(a, b, c, 0, 0, 0);
}

// ---------------------------------------------------------------------------
// K0: prep — fused weight hi/lo split (blocks 0..2047) + x transpose/split
// (blocks 2048..6143). One launch instead of two.
// ---------------------------------------------------------------------------
__global__ __launch_bounds__(256) void prep(
    const float* __restrict__ x,
    const float* __restrict__ s0, const float* __restrict__ s1,
    const float* __restrict__ s2, const float* __restrict__ s3,
    _Float16* __restrict__ d0h, _Float16* __restrict__ d0l,
    _Float16* __restrict__ d1h, _Float16* __restrict__ d1l,
    _Float16* __restrict__ d2h, _Float16* __restrict__ d2l,
    _Float16* __restrict__ d3h, _Float16* __restrict__ d3l,
    _Float16* __restrict__ xth, _Float16* __restrict__ xtl)
{
    __shared__ float lt[32][36];
    const int t = threadIdx.x;
    const int bid = blockIdx.x;
    if (bid < 2048) {
        const int seg = bid >> 9;
        const int i = (bid & 511) * 256 + t;
        const float* src = (seg == 0) ? s0 : (seg == 1) ? s1 : (seg == 2) ? s2 : s3;
        _Float16* dh = (seg == 0) ? d0h : (seg == 1) ? d1h : (seg == 2) ? d2h : d3h;
        _Float16* dl = (seg == 0) ? d0l : (seg == 1) ? d1l : (seg == 2) ? d2l : d3l;
        const float f = src[i];
        const _Float16 h = (_Float16)f;
        dh[i] = h;
        dl[i] = (_Float16)(f - (float)h);
    } else {
        const int bid2 = bid - 2048;
        const int c0 = (bid2 & 7) * 32, hw0 = ((bid2 >> 3) & 31) * 32, b = bid2 >> 8;
        {
            const int cl = t >> 3, hw4 = (t & 7) * 4;
            *(f32x4*)&lt[cl][hw4] = *(const f32x4*)&x[((size_t)(b * 256 + c0 + cl)) * 1024 + hw0 + hw4];
        }
        __syncthreads();
        {
            const int hwl = t >> 3, c4 = (t & 7) * 4;
            f16x4 hv, lv;
#pragma unroll
            for (int e = 0; e < 4; ++e) {
                const float f = lt[c4 + e][hwl];
                const _Float16 h = (_Float16)f;
                hv[e] = h;
                lv[e] = (_Float16)(f - (float)h);
            }
            const size_t off = ((size_t)(b * 1024 + hw0 + hwl)) * 256 + c0 + c4;
            *(f16x4*)(xth + off) = hv;
            *(f16x4*)(xtl + off) = lv;
        }
    }
}

// ---------------------------------------------------------------------------
// K1: QKV projection GEMM, split-f16 MFMA + BN fold.
// = R7 verbatim (75.9us best): 128n x 128o blocks, 256 thr / 4 waves,
// single-buffer LDS [128][72], XCD swizzle (FETCH 69->17MB verified),
// plain __launch_bounds__(256) -> 128V+64A, 2 blocks/CU, no spill.
// LEDGER (R4-R8): qkv is pinned at 2 blocks/CU.  o-tile shrink doubles HBM
// traffic (R4); 8-wave blocks spill (R5); reg caps <192 spill (R6); LDS
// dbuf (74.75KB / +8 VGPR) halves residency to 1 block/CU (R8).  This
// config is the local optimum — do not iterate further on qkv shape.
// ---------------------------------------------------------------------------
__global__ __launch_bounds__(256) void qkv_mfma(
    const _Float16* __restrict__ xth, const _Float16* __restrict__ xtl,
    const _Float16* __restrict__ wqh, const _Float16* __restrict__ wql,
    const _Float16* __restrict__ wkh, const _Float16* __restrict__ wkl,
    const _Float16* __restrict__ wvh, const _Float16* __restrict__ wvl,
    const float* __restrict__ gq, const float* __restrict__ bq, const float* __restrict__ mq, const float* __restrict__ vq,
    const float* __restrict__ gk, const float* __restrict__ bk, const float* __restrict__ mk, const float* __restrict__ vk,
    const float* __restrict__ gv, const float* __restrict__ bv, const float* __restrict__ mv, const float* __restrict__ vv,
    _Float16* __restrict__ qh, _Float16* __restrict__ ql,
    _Float16* __restrict__ kh,
    _Float16* __restrict__ vt)
{
    __shared__ _Float16 Ah[128][72];
    __shared__ _Float16 Al[128][72];
    __shared__ float sc_l[128], tc_l[128];

    const int t = threadIdx.x;
    // XCD swizzle: hw dispatch round-robins linear id across 8 XCDs; remap
    // so each XCD owns a contiguous chunk of logical ids (bn fastest).
    const int lin = blockIdx.x;            // 0..1535
    const int newid = (lin & 7) * 192 + (lin >> 3);
    const int bn = newid % 12;             // 0..11
    const int m0 = (newid / 12) * 128;
    const int proj = bn >> 2;
    const int o0 = (bn & 3) * 128;         // [0,512)
    const int bimg = m0 >> 10;
    const int nb = m0 & 1023;

    const _Float16* Wh = (proj == 0) ? wqh : (proj == 1) ? wkh : wvh;
    const _Float16* Wl = (proj == 0) ? wql : (proj == 1) ? wkl : wvl;
    const float* G  = (proj == 0) ? gq : (proj == 1) ? gk : gv;
    const float* Bt = (proj == 0) ? bq : (proj == 1) ? bk : bv;
    const float* Mn = (proj == 0) ? mq : (proj == 1) ? mk : mv;
    const float* Vr = (proj == 0) ? vq : (proj == 1) ? vk : vv;

    if (t < 128) {
        const int o = o0 + t;
        float s = G[o] / sqrtf(Vr[o] + 1e-5f);
        float tt = Bt[o] - Mn[o] * s;
        if (proj == 0) { s *= 0.125f; tt *= 0.125f; }
        sc_l[t] = s; tc_l[t] = tt;
    }

    const int wave = t >> 6, lane = t & 63;
    const int quad = lane >> 4, l16 = lane & 15;
    const int wm = (wave >> 1) * 64, wn = (wave & 1) * 64;

    f32x4 acc[4][4] = {};   // q/k: [nj][mi] ; v: [mi][nj]

    for (int c0 = 0; c0 < 256; c0 += 64) {
        __syncthreads();
        {   // stage x hi/lo tiles [128 n][64 c]
            int r = t >> 3;
            const int cs = (t & 7) * 8;
#pragma unroll
            for (int p = 0; p < 4; ++p, r += 32) {
                const size_t off = ((size_t)(bimg * 1024 + nb + r)) * 256 + c0 + cs;
                *(f16x8*)&Ah[r][cs] = *(const f16x8*)(xth + off);
                *(f16x8*)&Al[r][cs] = *(const f16x8*)(xtl + off);
            }
        }
        __syncthreads();
#pragma unroll
        for (int kk = 0; kk < 2; ++kk) {
            f16x8 ah[4], al[4], bh[4], bl[4];
#pragma unroll
            for (int mi = 0; mi < 4; ++mi) {
                ah[mi] = *(const f16x8*)&Ah[wm + mi * 16 + l16][kk * 32 + quad * 8];
                al[mi] = *(const f16x8*)&Al[wm + mi * 16 + l16][kk * 32 + quad * 8];
            }
#pragma unroll
            for (int nj = 0; nj < 4; ++nj) {
                const size_t off = ((size_t)(o0 + wn + nj * 16 + l16)) * 256 + c0 + kk * 32 + quad * 8;
                bh[nj] = *(const f16x8*)(Wh + off);
                if (proj < 2) bl[nj] = *(const f16x8*)(Wl + off);
            }
            if (proj < 2) {   // swapped: D rows = channels o, 3 terms
#pragma unroll
                for (int nj = 0; nj < 4; ++nj)
#pragma unroll
                    for (int mi = 0; mi < 4; ++mi) {
                        acc[nj][mi] = mfma16f(bh[nj], ah[mi], acc[nj][mi]);
                        acc[nj][mi] = mfma16f(bh[nj], al[mi], acc[nj][mi]);
                        acc[nj][mi] = mfma16f(bl[nj], ah[mi], acc[nj][mi]);
                    }
            } else {          // V: NON-swapped, D rows = n, 2 terms
#pragma unroll
                for (int mi = 0; mi < 4; ++mi)
#pragma unroll
                    for (int nj = 0; nj < 4; ++nj) {
                        acc[mi][nj] = mfma16f(ah[mi], bh[nj], acc[mi][nj]);
                        acc[mi][nj] = mfma16f(al[mi], bh[nj], acc[mi][nj]);
                    }
            }
        }
    }

    if (proj < 2) {
        _Float16* Oh = (proj == 0) ? qh : kh;
#pragma unroll
        for (int nj = 0; nj < 4; ++nj) {
            const int olb = wn + nj * 16 + quad * 4;     // local o base, 4 consecutive
            const int ob = o0 + olb;
            const int head = ob >> 6, d0 = ob & 63;
#pragma unroll
            for (int mi = 0; mi < 4; ++mi) {
                const int n = nb + wm + mi * 16 + l16;
                f16x4 hv, lv;
#pragma unroll
                for (int rr = 0; rr < 4; ++rr) {
                    const float val = acc[nj][mi][rr] * sc_l[olb + rr] + tc_l[olb + rr];
                    const _Float16 h = (_Float16)val;
                    hv[rr] = h;
                    lv[rr] = (_Float16)(val - (float)h);
                }
                const size_t off = (((size_t)(bimg * 8 + head)) * 1024 + n) * 64 + d0;
                *(f16x4*)(Oh + off) = hv;
                if (proj == 0) *(f16x4*)(ql + off) = lv;   // only q keeps the lo part
            }
        }
    } else {
#pragma unroll
        for (int nj = 0; nj < 4; ++nj) {
            const int olb = wn + nj * 16 + l16;
            const int o = o0 + olb;
            const int head = o >> 6, d = o & 63;
            const float s = sc_l[olb], tt = tc_l[olb];
#pragma unroll
            for (int mi = 0; mi < 4; ++mi) {
                const int n0 = nb + wm + mi * 16 + quad * 4;
                f16x4 v4;
#pragma unroll
                for (int rr = 0; rr < 4; ++rr) v4[rr] = (_Float16)(acc[mi][nj][rr] * s + tt);
                *(f16x4*)(vt + (((size_t)(bimg * 8 + head)) * 64 + d) * 1024 + n0) = v4;
            }
        }
    }
}

// ---------------------------------------------------------------------------
// K2: split-f16 MFMA flash attention + hardswish; fixed-max softmax (C=12).
// V5: 512-thread / 8-wave blocks, 16 q-rows/wave, __launch_bounds__(512,4)
// (128-reg total cap; (,8) spilled — gfx950 unified VGPR+AGPR file).
// S^T = mfma(K,Q) keeps P in registers; PV via 16x16x16.
// ---------------------------------------------------------------------------
__global__ __launch_bounds__(512, 4) void attn_mfma(
    const _Float16* __restrict__ qh, const _Float16* __restrict__ ql,
    const _Float16* __restrict__ kh,
    const _Float16* __restrict__ vt,
    const float* __restrict__ emb,
    _Float16* __restrict__ hsh)
{
    __shared__ float    emb_s[1024];
    __shared__ _Float16 kth[64][76];                // [j][d] staged K tile (hi)
    __shared__ _Float16 vts[64][76];                // [d][j] staged V tile

    const int t = threadIdx.x;
    const int bid = blockIdx.x;
    const int bh = bid & 127, qb = bid >> 7;
    const int b = bh >> 3, h = bh & 7;
    const int wave = t >> 6, lane = t & 63;
    const int quad = lane >> 4, l16 = lane & 15;
    const int q0 = qb * 128 + wave * 16;            // 16 q-rows per wave
    const float L2E = 1.44269504f;

    for (int i = t; i < 1024; i += 512) emb_s[i] = (8.0f * emb[i * 8 + h] - 12.0f) * L2E;

    const size_t base = (size_t)bh * 65536;   // q/k [n][64]; vT [64][n]

    f16x8 qfh[2], qfl[2];
#pragma unroll
    for (int kk = 0; kk < 2; ++kk) {
        const size_t off = base + (size_t)(q0 + l16) * 64 + kk * 32 + quad * 8;
        qfh[kk] = *(const f16x8*)(qh + off);
        qfl[kk] = *(const f16x8*)(ql + off);
    }

    // lane's query row: i = q0 + l16
    const int ig0 = q0 + l16;
    const int xi = ig0 >> 5, yi = ig0 & 31;

    // staging: 512 threads cover 64x64 K and 64x64 V with one f16x8 each
    const int sr = t >> 3;            // 0..63
    const int scs = (t & 7) * 8;

    f16x8 pkh, pvv;                   // prefetch registers (tile jb)
    pkh = *(const f16x8*)(kh + base + (size_t)sr * 64 + scs);              // jb = 0
    pvv = *(const f16x8*)(vt + base + (size_t)sr * 1024 + scs);

    f32x4 ao[4] = {};
    float lsum = 0.0f;

    for (int jb = 0; jb < 16; ++jb) {
        __syncthreads();   // prior tile's LDS reads done (also orders emb_s at jb=0)
        *(f16x8*)&kth[sr][scs] = pkh;
        *(f16x8*)&vts[sr][scs] = pvv;
        __syncthreads();
        if (jb < 15) {     // (jb+1) prefetch; latency hides behind compute
            pkh = *(const f16x8*)(kh + base + (size_t)((jb + 1) * 64 + sr) * 64 + scs);
            pvv = *(const f16x8*)(vt + base + (size_t)sr * 1024 + (jb + 1) * 64 + scs);
        }

        // per 16-j block: S^T -> softmax in regs -> PV (P stays in registers)
#pragma unroll
        for (int nj = 0; nj < 4; ++nj) {
            const f16x8 kf0 = *(const f16x8*)&kth[nj * 16 + l16][quad * 8];
            const f16x8 kf1 = *(const f16x8*)&kth[nj * 16 + l16][32 + quad * 8];

            // S^T tile: D[j][i]; rows j = nj*16 + quad*4 + r, cols i = l16
            f32x4 ss = {};
            __builtin_amdgcn_s_setprio(1);
            ss = mfma16f(kf0, qfh[0], ss);
            ss = mfma16f(kf0, qfl[0], ss);
            ss = mfma16f(kf1, qfh[1], ss);
            ss = mfma16f(kf1, qfl[1], ss);
            __builtin_amdgcn_s_setprio(0);

            const int xj = 2 * jb + (nj >> 1);
            const int yj0 = ((nj & 1) << 4) + quad * 4;
            const int dxo = abs(xi - xj) << 5;
            const int yq = yi - yj0;
            const float p0 = __builtin_amdgcn_exp2f(fmaf(ss[0], L2E, emb_s[dxo + abs(yq)]));
            const float p1 = __builtin_amdgcn_exp2f(fmaf(ss[1], L2E, emb_s[dxo + abs(yq - 1)]));
            const float p2 = __builtin_amdgcn_exp2f(fmaf(ss[2], L2E, emb_s[dxo + abs(yq - 2)]));
            const float p3 = __builtin_amdgcn_exp2f(fmaf(ss[3], L2E, emb_s[dxo + abs(yq - 3)]));
            lsum += (p0 + p1) + (p2 + p3);
            f16x4 pa;
            pa[0] = (_Float16)p0; pa[1] = (_Float16)p1;
            pa[2] = (_Float16)p2; pa[3] = (_Float16)p3;

            // V fragments: B[k=j][col=d]; k = quad*4+e -> vts[d][nj*16+quad*4+e]
            f16x4 vf[4];
#pragma unroll
            for (int dj = 0; dj < 4; ++dj)
                vf[dj] = *(const f16x4*)&vts[dj * 16 + l16][nj * 16 + quad * 4];
            __builtin_amdgcn_s_setprio(1);
#pragma unroll
            for (int dj = 0; dj < 4; ++dj)
                ao[dj] = __builtin_amdgcn_mfma_f32_16x16x16f16(pa, vf[dj], ao[dj], 0, 0, 0);
            __builtin_amdgcn_s_setprio(0);
        }
    }

    // final cross-quad sum, redistribute to C-layout rows, normalize,
    // hardswish, f16 hi-only store
    float l = lsum;
    l += __shfl_xor(l, 16, 64);
    l += __shfl_xor(l, 32, 64);     // all lanes: rowsum for i = q0 + l16
    float inv[4];
#pragma unroll
    for (int r = 0; r < 4; ++r)
        inv[r] = 1.0f / __shfl(l, quad * 4 + r, 64);
#pragma unroll
    for (int r = 0; r < 4; ++r) {
        const int ig = q0 + quad * 4 + r;
#pragma unroll
        for (int dj = 0; dj < 4; ++dj) {
            const float o = ao[dj][r] * inv[r];
            const float hsw = o * fminf(fmaxf(o + 3.0f, 0.0f), 6.0f) * (1.0f / 6.0f);
            hsh[((size_t)(b * 1024 + ig)) * 512 + h * 64 + dj * 16 + l16] = (_Float16)hsw;
        }
    }
}

// ---------------------------------------------------------------------------
// K3: output projection GEMM, split-f16 MFMA — 2 TERMS (hs hi-only).
// V2: one-shot A-staging + barrier-free K loop.  Old form had 4 staging
// phases x 2 barriers and a 128-VGPR manual B pipeline (~196 regs -> 2
// waves/SIMD).  New: 32m x 128o blocks (grid 512x2 = 1024 = 4/CU),
// Ah[32][520] = 33.3 KB staged once (8 coalesced wave-row instructions,
// 1024B contiguous each), ONE barrier, then 16 fully-unrolled iters of
// {8 B-frag loads + 1 ds_read + 8 MFMA} with no barriers — compiler is
// free to software-pipeline loads across iterations.  No manual prefetch
// regs: live set ~120 (bh/bl 64 + acc 16A + ah 8 + addr).  (256,3) caps
// at 170 with ample headroom (not an R6-style squeeze) -> 3 waves/SIMD,
// LDS allows 4 blocks/CU.  Row stride 520 f16 = 260 dw = 4 mod 32 ->
// 2-way bank aliasing (free).
// ---------------------------------------------------------------------------
__global__ __launch_bounds__(256, 3) void out_mfma(
    const _Float16* __restrict__ hsh,
    const _Float16* __restrict__ woh, const _Float16* __restrict__ wol,
    const float* __restrict__ b_out, const float* __restrict__ go, const float* __restrict__ bo,
    const float* __restrict__ mo, const float* __restrict__ vo, float* __restrict__ y)
{
    __shared__ _Float16 Ah[32][520];

    const int t = threadIdx.x;
    const int m0 = blockIdx.x * 32;
    const int o0 = blockIdx.y * 128;
    const int bimg = m0 >> 10, nb = m0 & 1023;
    const int wave = t >> 6, lane = t & 63;
    const int quad = lane >> 4, l16 = lane & 15;
    const int wm = (wave >> 1) * 16, wn = (wave & 1) * 64;

    // stage the full 32m x 512c hsh panel: one row per wave-instruction
#pragma unroll
    for (int p = 0; p < 8; ++p) {
        const int r = p * 4 + wave;
        *(f16x8*)&Ah[r][lane * 8] = *(const f16x8*)(hsh + ((size_t)(m0 + r)) * 512 + lane * 8);
    }

    f32x4 acc[4] = {};   // [nj]; D rows = n

    __syncthreads();   // A panel visible

#pragma unroll
    for (int it = 0; it < 16; ++it) {
        f16x8 bh[4], bl[4];
#pragma unroll
        for (int nj = 0; nj < 4; ++nj) {
            const size_t off = ((size_t)(o0 + wn + nj * 16 + l16)) * 512 + it * 32 + quad * 8;
            bh[nj] = *(const f16x8*)(woh + off);
            bl[nj] = *(const f16x8*)(wol + off);
        }
        const f16x8 ah = *(const f16x8*)&Ah[wm + l16][it * 32 + quad * 8];
#pragma unroll
        for (int nj = 0; nj < 4; ++nj) {
            acc[nj] = mfma16f(ah, bh[nj], acc[nj]);
            acc[nj] = mfma16f(ah, bl[nj], acc[nj]);
        }
    }

#pragma unroll
    for (int nj = 0; nj < 4; ++nj) {
        const int o = o0 + wn + nj * 16 + l16;
        const float s = go[o] / sqrtf(vo[o] + 1e-5f);
        const float tt = bo[o] - mo[o] * s;
        const float bf = b_out[o];
        const int hw = nb + wm + quad * 4;
        f32x4 v4;
#pragma unroll
        for (int rr = 0; rr < 4; ++rr) v4[rr] = (acc[nj][rr] + bf) * s + tt;
        *(f32x4*)&y[((size_t)(bimg * 256 + o)) * 1024 + hw] = v4;
    }
}

extern "C" void kernel_launch(void* const* d_in, const int* in_sizes, int n_in,
                              void* d_out, int out_size, void* d_ws, size_t ws_size,
                              hipStream_t stream) {
    const float* x     = (const float*)d_in[0];
    const float* wq    = (const float*)d_in[1];
    const float* gq    = (const float*)d_in[2];
    const float* bq    = (const float*)d_in[3];
    const float* mq    = (const float*)d_in[4];
    const float* vq    = (const float*)d_in[5];
    const float* wk    = (const float*)d_in[6];
    const float* gk    = (const float*)d_in[7];
    const float* bk    = (const float*)d_in[8];
    const float* mk    = (const float*)d_in[9];
    const float* vk    = (const float*)d_in[10];
    const float* wv    = (const float*)d_in[11];
    const float* gv    = (const float*)d_in[12];
    const float* bv    = (const float*)d_in[13];
    const float* mv    = (const float*)d_in[14];
    const float* vv    = (const float*)d_in[15];
    const float* emb   = (const float*)d_in[16];
    const float* w_out = (const float*)d_in[17];
    const float* b_out = (const float*)d_in[18];
    const float* go    = (const float*)d_in[19];
    const float* bo    = (const float*)d_in[20];
    const float* mo    = (const float*)d_in[21];
    const float* vo    = (const float*)d_in[22];
    // d_in[23] = pos_indices — computed analytically in-kernel, unused.

    // Workspace (in _Float16 elements); peak < proven 136.3 MB.
    _Float16* us = (_Float16*)d_ws;
    // Union region [0, 16,777,216): xth/xtl early, hsh late (x dead by attn).
    _Float16* xth = us;                        // [16][1024][256]
    _Float16* xtl = us + 4194304;
    _Float16* hsh = us;                        // [16][1024][512] (hi-only)
    _Float16* wsp = us + 16777216;             // weight splits, 8 x 131072
    _Float16* wqh = wsp,            *wql = wsp + 131072;
    _Float16* wkh = wsp + 262144,   *wkl = wsp + 393216;
    _Float16* wvh = wsp + 524288,   *wvl = wsp + 655360;
    _Float16* woh = wsp + 786432,   *wol = wsp + 917504;
    _Float16* qv  = us + 17825792;
    _Float16* qhw = qv,             *qlw = qv + 8388608;   // [16][8][1024][64]
    _Float16* khw = qv + 16777216;                          // [16][8][1024][64] (hi only)
    _Float16* vtw = qv + 33554432;                          // [16][8][64][1024]

    prep<<<6144, 256, 0, stream>>>(x, wq, wk, wv, w_out,
                                   wqh, wql, wkh, wkl, wvh, wvl, woh, wol,
                                   xth, xtl);

    qkv_mfma<<<1536, 256, 0, stream>>>(
        xth, xtl, wqh, wql, wkh, wkl, wvh, wvl,
        gq, bq, mq, vq, gk, bk, mk, vk, gv, bv, mv, vv,
        qhw, qlw, khw, vtw);

    attn_mfma<<<1024, 512, 0, stream>>>(
        qhw, qlw, khw, vtw, emb, hsh);

    out_mfma<<<dim3(512, 2), 256, 0, stream>>>(
        hsh, woh, wol, b_out, go, bo, mo, vo, (float*)d_out);
}

// Round 10
// 272.104 us; speedup vs baseline: 1.1180x; 1.1180x over previous
//
#include <hip/hip_runtime.h>

typedef __attribute__((ext_vector_type(4))) float f32x4;
typedef __attribute__((ext_vector_type(8))) _Float16 f16x8;
typedef __attribute__((ext_vector_type(4))) _Float16 f16x4;

static __device__ __forceinline__ f32x4 mfma16f(f16x8 a, f16x8 b, f32x4 c) {
    return __builtin_amdgcn_mfma_f32_16x16x32_f16(a, b, c, 0, 0, 0);
}

// ---------------------------------------------------------------------------
// K0: prep — fused weight hi/lo split (blocks 0..2047) + x transpose/split
// (blocks 2048..6143). One launch instead of two.
// NOTE (R9 accounting): prep is estimated 60-75us vs ~17us roofline — next
// target once it becomes visible in top-5.
// ---------------------------------------------------------------------------
__global__ __launch_bounds__(256) void prep(
    const float* __restrict__ x,
    const float* __restrict__ s0, const float* __restrict__ s1,
    const float* __restrict__ s2, const float* __restrict__ s3,
    _Float16* __restrict__ d0h, _Float16* __restrict__ d0l,
    _Float16* __restrict__ d1h, _Float16* __restrict__ d1l,
    _Float16* __restrict__ d2h, _Float16* __restrict__ d2l,
    _Float16* __restrict__ d3h, _Float16* __restrict__ d3l,
    _Float16* __restrict__ xth, _Float16* __restrict__ xtl)
{
    __shared__ float lt[32][36];
    const int t = threadIdx.x;
    const int bid = blockIdx.x;
    if (bid < 2048) {
        const int seg = bid >> 9;
        const int i = (bid & 511) * 256 + t;
        const float* src = (seg == 0) ? s0 : (seg == 1) ? s1 : (seg == 2) ? s2 : s3;
        _Float16* dh = (seg == 0) ? d0h : (seg == 1) ? d1h : (seg == 2) ? d2h : d3h;
        _Float16* dl = (seg == 0) ? d0l : (seg == 1) ? d1l : (seg == 2) ? d2l : d3l;
        const float f = src[i];
        const _Float16 h = (_Float16)f;
        dh[i] = h;
        dl[i] = (_Float16)(f - (float)h);
    } else {
        const int bid2 = bid - 2048;
        const int c0 = (bid2 & 7) * 32, hw0 = ((bid2 >> 3) & 31) * 32, b = bid2 >> 8;
        {
            const int cl = t >> 3, hw4 = (t & 7) * 4;
            *(f32x4*)&lt[cl][hw4] = *(const f32x4*)&x[((size_t)(b * 256 + c0 + cl)) * 1024 + hw0 + hw4];
        }
        __syncthreads();
        {
            const int hwl = t >> 3, c4 = (t & 7) * 4;
            f16x4 hv, lv;
#pragma unroll
            for (int e = 0; e < 4; ++e) {
                const float f = lt[c4 + e][hwl];
                const _Float16 h = (_Float16)f;
                hv[e] = h;
                lv[e] = (_Float16)(f - (float)h);
            }
            const size_t off = ((size_t)(b * 1024 + hw0 + hwl)) * 256 + c0 + c4;
            *(f16x4*)(xth + off) = hv;
            *(f16x4*)(xtl + off) = lv;
        }
    }
}

// ---------------------------------------------------------------------------
// K1: QKV projection GEMM, split-f16 MFMA + BN fold.
// V7 = R7 tiling/traffic (pinned: 128n x 128o, 4 waves, XCD swizzle,
// FETCH=17MB) with staging swapped to global_load_lds DMA (R4's verified
// mechanism: linear LDS [128][64], per-lane GLOBAL source column swizzled
// slot^=(row&7), fragment reads apply same XOR — rule #21 both-sides).
// Removes the load->VGPR->ds_write dependency chain + staging address VALU
// from the latency-bound staging phase; frees ~16 staging VGPRs.
// R4 measured this staging at 0 bank conflicts (pad-72's 1.57M gone).
// ---------------------------------------------------------------------------
__global__ __launch_bounds__(256) void qkv_mfma(
    const _Float16* __restrict__ xth, const _Float16* __restrict__ xtl,
    const _Float16* __restrict__ wqh, const _Float16* __restrict__ wql,
    const _Float16* __restrict__ wkh, const _Float16* __restrict__ wkl,
    const _Float16* __restrict__ wvh, const _Float16* __restrict__ wvl,
    const float* __restrict__ gq, const float* __restrict__ bq, const float* __restrict__ mq, const float* __restrict__ vq,
    const float* __restrict__ gk, const float* __restrict__ bk, const float* __restrict__ mk, const float* __restrict__ vk,
    const float* __restrict__ gv, const float* __restrict__ bv, const float* __restrict__ mv, const float* __restrict__ vv,
    _Float16* __restrict__ qh, _Float16* __restrict__ ql,
    _Float16* __restrict__ kh,
    _Float16* __restrict__ vt)
{
    __shared__ _Float16 Ah[128][64];
    __shared__ _Float16 Al[128][64];
    __shared__ float sc_l[128], tc_l[128];

    const int t = threadIdx.x;
    // XCD swizzle: each XCD owns a contiguous chunk of logical ids.
    const int lin = blockIdx.x;            // 0..1535
    const int newid = (lin & 7) * 192 + (lin >> 3);
    const int bn = newid % 12;             // 0..11
    const int m0 = (newid / 12) * 128;
    const int proj = bn >> 2;
    const int o0 = (bn & 3) * 128;         // [0,512)
    const int bimg = m0 >> 10;
    const int nb = m0 & 1023;

    const _Float16* Wh = (proj == 0) ? wqh : (proj == 1) ? wkh : wvh;
    const _Float16* Wl = (proj == 0) ? wql : (proj == 1) ? wkl : wvl;
    const float* G  = (proj == 0) ? gq : (proj == 1) ? gk : gv;
    const float* Bt = (proj == 0) ? bq : (proj == 1) ? bk : bv;
    const float* Mn = (proj == 0) ? mq : (proj == 1) ? mk : mv;
    const float* Vr = (proj == 0) ? vq : (proj == 1) ? vk : vv;

    if (t < 128) {
        const int o = o0 + t;
        float s = G[o] / sqrtf(Vr[o] + 1e-5f);
        float tt = Bt[o] - Mn[o] * s;
        if (proj == 0) { s *= 0.125f; tt *= 0.125f; }
        sc_l[t] = s; tc_l[t] = tt;
    }

    const int wave = t >> 6, lane = t & 63;
    const int quad = lane >> 4, l16 = lane & 15;
    const int wm = (wave >> 1) * 64, wn = (wave & 1) * 64;

    // DMA staging geometry: wave covers rows [wave*32, wave*32+32);
    // each gload_lds instr fills 8 rows (64 lanes x 16B = 1024B linear).
    const int lr8 = lane >> 3;           // row within 8-row group
    const int lsl = lane & 7;            // LDS slot this lane fills

    f32x4 acc[4][4] = {};   // q/k: [nj][mi] ; v: [mi][nj]

    for (int c0 = 0; c0 < 256; c0 += 64) {
        __syncthreads();   // prior tile's LDS reads done before DMA overwrite
#pragma unroll
        for (int p = 0; p < 4; ++p) {
            const int r = wave * 32 + p * 8 + lr8;
            const int sg = lsl ^ (r & 7);          // pre-swizzled source col
            const size_t goff = ((size_t)(bimg * 1024 + nb + r)) * 256 + c0 + sg * 8;
            __builtin_amdgcn_global_load_lds(
                (const __attribute__((address_space(1))) void*)(xth + goff),
                (__attribute__((address_space(3))) void*)&Ah[wave * 32 + p * 8][0], 16, 0, 0);
            __builtin_amdgcn_global_load_lds(
                (const __attribute__((address_space(1))) void*)(xtl + goff),
                (__attribute__((address_space(3))) void*)&Al[wave * 32 + p * 8][0], 16, 0, 0);
        }
        __syncthreads();   // vmcnt drained -> tiles visible
#pragma unroll
        for (int kk = 0; kk < 2; ++kk) {
            f16x8 ah[4], al[4], bh[4], bl[4];
#pragma unroll
            for (int mi = 0; mi < 4; ++mi) {
                const int arow = wm + mi * 16 + l16;
                const int sl = ((kk * 4 + quad) ^ (arow & 7)) * 8;   // swizzled read
                ah[mi] = *(const f16x8*)&Ah[arow][sl];
                al[mi] = *(const f16x8*)&Al[arow][sl];
            }
#pragma unroll
            for (int nj = 0; nj < 4; ++nj) {
                const size_t off = ((size_t)(o0 + wn + nj * 16 + l16)) * 256 + c0 + kk * 32 + quad * 8;
                bh[nj] = *(const f16x8*)(Wh + off);
                if (proj < 2) bl[nj] = *(const f16x8*)(Wl + off);
            }
            if (proj < 2) {   // swapped: D rows = channels o, 3 terms
#pragma unroll
                for (int nj = 0; nj < 4; ++nj)
#pragma unroll
                    for (int mi = 0; mi < 4; ++mi) {
                        acc[nj][mi] = mfma16f(bh[nj], ah[mi], acc[nj][mi]);
                        acc[nj][mi] = mfma16f(bh[nj], al[mi], acc[nj][mi]);
                        acc[nj][mi] = mfma16f(bl[nj], ah[mi], acc[nj][mi]);
                    }
            } else {          // V: NON-swapped, D rows = n, 2 terms
#pragma unroll
                for (int mi = 0; mi < 4; ++mi)
#pragma unroll
                    for (int nj = 0; nj < 4; ++nj) {
                        acc[mi][nj] = mfma16f(ah[mi], bh[nj], acc[mi][nj]);
                        acc[mi][nj] = mfma16f(al[mi], bh[nj], acc[mi][nj]);
                    }
            }
        }
    }

    if (proj < 2) {
        _Float16* Oh = (proj == 0) ? qh : kh;
#pragma unroll
        for (int nj = 0; nj < 4; ++nj) {
            const int olb = wn + nj * 16 + quad * 4;     // local o base, 4 consecutive
            const int ob = o0 + olb;
            const int head = ob >> 6, d0 = ob & 63;
#pragma unroll
            for (int mi = 0; mi < 4; ++mi) {
                const int n = nb + wm + mi * 16 + l16;
                f16x4 hv, lv;
#pragma unroll
                for (int rr = 0; rr < 4; ++rr) {
                    const float val = acc[nj][mi][rr] * sc_l[olb + rr] + tc_l[olb + rr];
                    const _Float16 h = (_Float16)val;
                    hv[rr] = h;
                    lv[rr] = (_Float16)(val - (float)h);
                }
                const size_t off = (((size_t)(bimg * 8 + head)) * 1024 + n) * 64 + d0;
                *(f16x4*)(Oh + off) = hv;
                if (proj == 0) *(f16x4*)(ql + off) = lv;   // only q keeps the lo part
            }
        }
    } else {
#pragma unroll
        for (int nj = 0; nj < 4; ++nj) {
            const int olb = wn + nj * 16 + l16;
            const int o = o0 + olb;
            const int head = o >> 6, d = o & 63;
            const float s = sc_l[olb], tt = tc_l[olb];
#pragma unroll
            for (int mi = 0; mi < 4; ++mi) {
                const int n0 = nb + wm + mi * 16 + quad * 4;
                f16x4 v4;
#pragma unroll
                for (int rr = 0; rr < 4; ++rr) v4[rr] = (_Float16)(acc[mi][nj][rr] * s + tt);
                *(f16x4*)(vt + (((size_t)(bimg * 8 + head)) * 64 + d) * 1024 + n0) = v4;
            }
        }
    }
}

// ---------------------------------------------------------------------------
// K2: split-f16 MFMA flash attention + hardswish; fixed-max softmax (C=12).
// V5: 512-thread / 8-wave blocks, 16 q-rows/wave, __launch_bounds__(512,4)
// (128-reg total cap; (,8) spilled — gfx950 unified VGPR+AGPR file).
// S^T = mfma(K,Q) keeps P in registers; PV via 16x16x16.
// ---------------------------------------------------------------------------
__global__ __launch_bounds__(512, 4) void attn_mfma(
    const _Float16* __restrict__ qh, const _Float16* __restrict__ ql,
    const _Float16* __restrict__ kh,
    const _Float16* __restrict__ vt,
    const float* __restrict__ emb,
    _Float16* __restrict__ hsh)
{
    __shared__ float    emb_s[1024];
    __shared__ _Float16 kth[64][76];                // [j][d] staged K tile (hi)
    __shared__ _Float16 vts[64][76];                // [d][j] staged V tile

    const int t = threadIdx.x;
    const int bid = blockIdx.x;
    const int bh = bid & 127, qb = bid >> 7;
    const int b = bh >> 3, h = bh & 7;
    const int wave = t >> 6, lane = t & 63;
    const int quad = lane >> 4, l16 = lane & 15;
    const int q0 = qb * 128 + wave * 16;            // 16 q-rows per wave
    const float L2E = 1.44269504f;

    for (int i = t; i < 1024; i += 512) emb_s[i] = (8.0f * emb[i * 8 + h] - 12.0f) * L2E;

    const size_t base = (size_t)bh * 65536;   // q/k [n][64]; vT [64][n]

    f16x8 qfh[2], qfl[2];
#pragma unroll
    for (int kk = 0; kk < 2; ++kk) {
        const size_t off = base + (size_t)(q0 + l16) * 64 + kk * 32 + quad * 8;
        qfh[kk] = *(const f16x8*)(qh + off);
        qfl[kk] = *(const f16x8*)(ql + off);
    }

    // lane's query row: i = q0 + l16
    const int ig0 = q0 + l16;
    const int xi = ig0 >> 5, yi = ig0 & 31;

    // staging: 512 threads cover 64x64 K and 64x64 V with one f16x8 each
    const int sr = t >> 3;            // 0..63
    const int scs = (t & 7) * 8;

    f16x8 pkh, pvv;                   // prefetch registers (tile jb)
    pkh = *(const f16x8*)(kh + base + (size_t)sr * 64 + scs);              // jb = 0
    pvv = *(const f16x8*)(vt + base + (size_t)sr * 1024 + scs);

    f32x4 ao[4] = {};
    float lsum = 0.0f;

    for (int jb = 0; jb < 16; ++jb) {
        __syncthreads();   // prior tile's LDS reads done (also orders emb_s at jb=0)
        *(f16x8*)&kth[sr][scs] = pkh;
        *(f16x8*)&vts[sr][scs] = pvv;
        __syncthreads();
        if (jb < 15) {     // (jb+1) prefetch; latency hides behind compute
            pkh = *(const f16x8*)(kh + base + (size_t)((jb + 1) * 64 + sr) * 64 + scs);
            pvv = *(const f16x8*)(vt + base + (size_t)sr * 1024 + (jb + 1) * 64 + scs);
        }

        // per 16-j block: S^T -> softmax in regs -> PV (P stays in registers)
#pragma unroll
        for (int nj = 0; nj < 4; ++nj) {
            const f16x8 kf0 = *(const f16x8*)&kth[nj * 16 + l16][quad * 8];
            const f16x8 kf1 = *(const f16x8*)&kth[nj * 16 + l16][32 + quad * 8];

            // S^T tile: D[j][i]; rows j = nj*16 + quad*4 + r, cols i = l16
            f32x4 ss = {};
            __builtin_amdgcn_s_setprio(1);
            ss = mfma16f(kf0, qfh[0], ss);
            ss = mfma16f(kf0, qfl[0], ss);
            ss = mfma16f(kf1, qfh[1], ss);
            ss = mfma16f(kf1, qfl[1], ss);
            __builtin_amdgcn_s_setprio(0);

            const int xj = 2 * jb + (nj >> 1);
            const int yj0 = ((nj & 1) << 4) + quad * 4;
            const int dxo = abs(xi - xj) << 5;
            const int yq = yi - yj0;
            const float p0 = __builtin_amdgcn_exp2f(fmaf(ss[0], L2E, emb_s[dxo + abs(yq)]));
            const float p1 = __builtin_amdgcn_exp2f(fmaf(ss[1], L2E, emb_s[dxo + abs(yq - 1)]));
            const float p2 = __builtin_amdgcn_exp2f(fmaf(ss[2], L2E, emb_s[dxo + abs(yq - 2)]));
            const float p3 = __builtin_amdgcn_exp2f(fmaf(ss[3], L2E, emb_s[dxo + abs(yq - 3)]));
            lsum += (p0 + p1) + (p2 + p3);
            f16x4 pa;
            pa[0] = (_Float16)p0; pa[1] = (_Float16)p1;
            pa[2] = (_Float16)p2; pa[3] = (_Float16)p3;

            // V fragments: B[k=j][col=d]; k = quad*4+e -> vts[d][nj*16+quad*4+e]
            f16x4 vf[4];
#pragma unroll
            for (int dj = 0; dj < 4; ++dj)
                vf[dj] = *(const f16x4*)&vts[dj * 16 + l16][nj * 16 + quad * 4];
            __builtin_amdgcn_s_setprio(1);
#pragma unroll
            for (int dj = 0; dj < 4; ++dj)
                ao[dj] = __builtin_amdgcn_mfma_f32_16x16x16f16(pa, vf[dj], ao[dj], 0, 0, 0);
            __builtin_amdgcn_s_setprio(0);
        }
    }

    // final cross-quad sum, redistribute to C-layout rows, normalize,
    // hardswish, f16 hi-only store
    float l = lsum;
    l += __shfl_xor(l, 16, 64);
    l += __shfl_xor(l, 32, 64);     // all lanes: rowsum for i = q0 + l16
    float inv[4];
#pragma unroll
    for (int r = 0; r < 4; ++r)
        inv[r] = 1.0f / __shfl(l, quad * 4 + r, 64);
#pragma unroll
    for (int r = 0; r < 4; ++r) {
        const int ig = q0 + quad * 4 + r;
#pragma unroll
        for (int dj = 0; dj < 4; ++dj) {
            const float o = ao[dj][r] * inv[r];
            const float hsw = o * fminf(fmaxf(o + 3.0f, 0.0f), 6.0f) * (1.0f / 6.0f);
            hsh[((size_t)(b * 1024 + ig)) * 512 + h * 64 + dj * 16 + l16] = (_Float16)hsw;
        }
    }
}

// ---------------------------------------------------------------------------
// K3: output projection GEMM, split-f16 MFMA — 2 TERMS (hs hi-only).
// = R7 verbatim (R9's 32m one-shot variant regressed +19us: halved
// MFMA-per-W-byte put the 8 global B-loads on the critical path).
// 64m x 128o tiles, BK=128, flattened 16-iter loop, pipelined B prefetch.
// ---------------------------------------------------------------------------
__global__ __launch_bounds__(256) void out_mfma(
    const _Float16* __restrict__ hsh,
    const _Float16* __restrict__ woh, const _Float16* __restrict__ wol,
    const float* __restrict__ b_out, const float* __restrict__ go, const float* __restrict__ bo,
    const float* __restrict__ mo, const float* __restrict__ vo, float* __restrict__ y)
{
    __shared__ _Float16 Ah[64][136];

    const int t = threadIdx.x;
    const int m0 = blockIdx.x * 64;
    const int o0 = blockIdx.y * 128;
    const int bimg = m0 >> 10, nb = m0 & 1023;
    const int wave = t >> 6, lane = t & 63;
    const int quad = lane >> 4, l16 = lane & 15;
    const int wm = (wave >> 1) * 32, wn = (wave & 1) * 64;

    f32x4 acc[2][4] = {};
    f16x8 bh[4], bl[4], nbh[4], nbl[4];

    // preload B fragments for iteration 0 (c0=0, kk=0)
#pragma unroll
    for (int nj = 0; nj < 4; ++nj) {
        const size_t off = ((size_t)(o0 + wn + nj * 16 + l16)) * 512 + quad * 8;
        bh[nj] = *(const f16x8*)(woh + off);
        bl[nj] = *(const f16x8*)(wol + off);
    }

#pragma unroll
    for (int it = 0; it < 16; ++it) {
        const int c0 = (it >> 2) * 128, kk = it & 3;
        if (kk == 0) {
            __syncthreads();
            const int cs = (t & 7) * 16;
#pragma unroll
            for (int p = 0; p < 2; ++p) {
                const int r = (t >> 3) + p * 32;
                *(f16x8*)&Ah[r][cs]     = *(const f16x8*)(hsh + ((size_t)(m0 + r)) * 512 + c0 + cs);
                *(f16x8*)&Ah[r][cs + 8] = *(const f16x8*)(hsh + ((size_t)(m0 + r)) * 512 + c0 + cs + 8);
            }
            __syncthreads();
        }
        if (it < 15) {   // prefetch next iteration's B fragments
            const int nit = it + 1;
            const int nc0 = (nit >> 2) * 128, nkk = nit & 3;
#pragma unroll
            for (int nj = 0; nj < 4; ++nj) {
                const size_t off = ((size_t)(o0 + wn + nj * 16 + l16)) * 512 + nc0 + nkk * 32 + quad * 8;
                nbh[nj] = *(const f16x8*)(woh + off);
                nbl[nj] = *(const f16x8*)(wol + off);
            }
        }
        f16x8 ah[2];
#pragma unroll
        for (int mi = 0; mi < 2; ++mi)
            ah[mi] = *(const f16x8*)&Ah[wm + mi * 16 + l16][kk * 32 + quad * 8];
#pragma unroll
        for (int mi = 0; mi < 2; ++mi)
#pragma unroll
            for (int nj = 0; nj < 4; ++nj) {
                acc[mi][nj] = mfma16f(ah[mi], bh[nj], acc[mi][nj]);
                acc[mi][nj] = mfma16f(ah[mi], bl[nj], acc[mi][nj]);
            }
#pragma unroll
        for (int nj = 0; nj < 4; ++nj) { bh[nj] = nbh[nj]; bl[nj] = nbl[nj]; }
    }

#pragma unroll
    for (int nj = 0; nj < 4; ++nj) {
        const int o = o0 + wn + nj * 16 + l16;
        const float s = go[o] / sqrtf(vo[o] + 1e-5f);
        const float tt = bo[o] - mo[o] * s;
        const float bf = b_out[o];
#pragma unroll
        for (int mi = 0; mi < 2; ++mi) {
            const int hw = nb + wm + mi * 16 + quad * 4;
            f32x4 v4;
#pragma unroll
            for (int rr = 0; rr < 4; ++rr) v4[rr] = (acc[mi][nj][rr] + bf) * s + tt;
            *(f32x4*)&y[((size_t)(bimg * 256 + o)) * 1024 + hw] = v4;
        }
    }
}

extern "C" void kernel_launch(void* const* d_in, const int* in_sizes, int n_in,
                              void* d_out, int out_size, void* d_ws, size_t ws_size,
                              hipStream_t stream) {
    const float* x     = (const float*)d_in[0];
    const float* wq    = (const float*)d_in[1];
    const float* gq    = (const float*)d_in[2];
    const float* bq    = (const float*)d_in[3];
    const float* mq    = (const float*)d_in[4];
    const float* vq    = (const float*)d_in[5];
    const float* wk    = (const float*)d_in[6];
    const float* gk    = (const float*)d_in[7];
    const float* bk    = (const float*)d_in[8];
    const float* mk    = (const float*)d_in[9];
    const float* vk    = (const float*)d_in[10];
    const float* wv    = (const float*)d_in[11];
    const float* gv    = (const float*)d_in[12];
    const float* bv    = (const float*)d_in[13];
    const float* mv    = (const float*)d_in[14];
    const float* vv    = (const float*)d_in[15];
    const float* emb   = (const float*)d_in[16];
    const float* w_out = (const float*)d_in[17];
    const float* b_out = (const float*)d_in[18];
    const float* go    = (const float*)d_in[19];
    const float* bo    = (const float*)d_in[20];
    const float* mo    = (const float*)d_in[21];
    const float* vo    = (const float*)d_in[22];
    // d_in[23] = pos_indices — computed analytically in-kernel, unused.

    // Workspace (in _Float16 elements); peak < proven 136.3 MB.
    _Float16* us = (_Float16*)d_ws;
    // Union region [0, 16,777,216): xth/xtl early, hsh late (x dead by attn).
    _Float16* xth = us;                        // [16][1024][256]
    _Float16* xtl = us + 4194304;
    _Float16* hsh = us;                        // [16][1024][512] (hi-only)
    _Float16* wsp = us + 16777216;             // weight splits, 8 x 131072
    _Float16* wqh = wsp,            *wql = wsp + 131072;
    _Float16* wkh = wsp + 262144,   *wkl = wsp + 393216;
    _Float16* wvh = wsp + 524288,   *wvl = wsp + 655360;
    _Float16* woh = wsp + 786432,   *wol = wsp + 917504;
    _Float16* qv  = us + 17825792;
    _Float16* qhw = qv,             *qlw = qv + 8388608;   // [16][8][1024][64]
    _Float16* khw = qv + 16777216;                          // [16][8][1024][64] (hi only)
    _Float16* vtw = qv + 33554432;                          // [16][8][64][1024]

    prep<<<6144, 256, 0, stream>>>(x, wq, wk, wv, w_out,
                                   wqh, wql, wkh, wkl, wvh, wvl, woh, wol,
                                   xth, xtl);

    qkv_mfma<<<1536, 256, 0, stream>>>(
        xth, xtl, wqh, wql, wkh, wkl, wvh, wvl,
        gq, bq, mq, vq, gk, bk, mk, vk, gv, bv, mv, vv,
        qhw, qlw, khw, vtw);

    attn_mfma<<<1024, 512, 0, stream>>>(
        qhw, qlw, khw, vtw, emb, hsh);

    out_mfma<<<dim3(256, 2), 256, 0, stream>>>(
        hsh, woh, wol, b_out, go, bo, mo, vo, (float*)d_out);
}